// Round 11
// baseline (1143.936 us; speedup 1.0000x reference)
//
#include <hip/hip_runtime.h>

#define SEQ 2048
#define BATCH 512
#define HDIM 128

typedef float f32x2 __attribute__((ext_vector_type(2)));

// tanh with input pre-scaled by 2*log2(e): tanh(x) = 1 - 2/(2^(x*2log2e)+1).
// Raw v_exp_f32 (2^y); saturates correctly at +/-inf.
__device__ __forceinline__ float tanh_e2(float y) {
    float e;
    asm("v_exp_f32 %0, %1" : "=v"(e) : "v"(y));
    return fmaf(-2.0f, __builtin_amdgcn_rcpf(e + 1.0f), 1.0f);
}

// x + dpp(x); bound_ctrl=true -> out-of-range lanes read 0.
template<int CTRL>
__device__ __forceinline__ float dpp_add(float x) {
    return x + __int_as_float(__builtin_amdgcn_update_dpp(
        0, __float_as_int(x), CTRL, 0xf, 0xf, true));
}

__global__ __launch_bounds__(512, 1)
void odenet_scan_kernel(const float* __restrict__ x,
                        const float* __restrict__ W1,
                        const float* __restrict__ b1,
                        const float* __restrict__ W2,
                        const float* __restrict__ b2,
                        const float* __restrict__ W3,
                        const float* __restrict__ b3,
                        float* __restrict__ out)
{
    const int t  = threadIdx.x;
    const int l  = t & 63;            // lane
    const int wv = t >> 6;            // wave 0..7
    const int ch = wv >> 2;           // chain: 0 (waves 0-3), 1 (waves 4-7)
    const int w  = wv & 3;            // wave within chain: cols [32w, 32w+32)
    const int g  = l >> 3;            // col group 0..7: cols c0..c0+3
    const int ke = l & 7;             // K-eighth: k in [16ke, 16ke+16)
    const int c0 = 32 * w + 4 * g;    // first of this lane's 4 output columns
    const int b0 = 2 * blockIdx.x;    // chains b0 (ch=0), b0+1 (ch=1)

    constexpr float CS = 2.8853900817779268f;   // 2*log2(e), tanh prefold

    __shared__ float2 xbuf[SEQ];           // 16 KB: {x_chainA, x_chainB}
    __shared__ float  h1buf[8][4 * 36];    // per-wave padded h1 (group g' at 36g')
    __shared__ float  ybuf[2][8];          // [parity][wave] scalar y-partials

    // ---- one-time: preload x for both chains (adjacent in memory).
    {
        float2 v[4];
        #pragma unroll
        for (int i = 0; i < 4; ++i)
            v[i] = *reinterpret_cast<const float2*>(&x[(i * 512 + t) * BATCH + b0]);
        #pragma unroll
        for (int i = 0; i < 4; ++i)
            xbuf[i * 512 + t] = v[i];
    }

    // ---- one-time: pin W2 sub-block: 4 cols x 16 K, K-packed f32x2,
    //      pre-scaled by CS (folds the tanh input scale into the matvec).
    f32x2 wc0[8], wc1[8], wc2[8], wc3[8];
    #pragma unroll
    for (int j = 0; j < 8; ++j) {
        const int k0 = 16 * ke + 2 * j;
        float4 a = *reinterpret_cast<const float4*>(&W2[k0 * HDIM + c0]);
        float4 b = *reinterpret_cast<const float4*>(&W2[(k0 + 1) * HDIM + c0]);
        wc0[j] = f32x2{a.x * CS, b.x * CS};
        wc1[j] = f32x2{a.y * CS, b.y * CS};
        wc2[j] = f32x2{a.z * CS, b.z * CS};
        wc3[j] = f32x2{a.w * CS, b.w * CS};
    }

    // h1 params (cols 2l, 2l+1 per wave), pre-scaled by CS.
    const float2 w1x_ = *reinterpret_cast<const float2*>(&W1[2 * l]);
    const float2 w1s_ = *reinterpret_cast<const float2*>(&W1[HDIM + 2 * l]);
    const float2 b1v_ = *reinterpret_cast<const float2*>(&b1[2 * l]);
    const float2 w1x = make_float2(w1x_.x * CS, w1x_.y * CS);
    const float2 w1s = make_float2(w1s_.x * CS, w1s_.y * CS);
    const float2 b1v = make_float2(b1v_.x * CS, b1v_.y * CS);
    // layer-2/3 params for cols c0..c0+3: b2 pre-scaled by CS;
    // w3 pre-scaled by 1/8 (each col's z duplicated x8 after the combine).
    const float4 b2v_ = *reinterpret_cast<const float4*>(&b2[c0]);
    const float4 b2v = make_float4(b2v_.x * CS, b2v_.y * CS, b2v_.z * CS, b2v_.w * CS);
    const float w3s0 = W3[(c0 + 0) * 2 + 1] * 0.125f;
    const float w3s1 = W3[(c0 + 1) * 2 + 1] * 0.125f;
    const float w3s2 = W3[(c0 + 2) * 2 + 1] * 0.125f;
    const float w3s3 = W3[(c0 + 3) * 2 + 1] * 0.125f;
    const float b31  = b3[1];

    // h write offset: position p=2l -> group p>>5 (=l>>4), slot p&31.
    const int hoff = 36 * (l >> 4) + ((2 * l) & 31);
    // h read base: K-window [16ke,16ke+16) -> group ke>>1, half (ke&1)*16.
    // The 8 bases {0,16,36,52,72,88,108,124} are pairwise distinct mod 32
    // at b128 granularity -> conflict-free.
    const float4* h4 = reinterpret_cast<const float4*>(
        &h1buf[wv][36 * (ke >> 1) + 16 * (ke & 1)]);

    __syncthreads();   // preload visible to all waves

    float s = 0.0f;
    float s_hold = 0.0f;
    float2 x0p = xbuf[0];
    float xc = ch ? x0p.y : x0p.x;
    float2 pre1 = make_float2(fmaf(w1x.x, xc, b1v.x), fmaf(w1x.y, xc, b1v.y));

    for (int n = 0; n < SEQ; ++n) {
        const int par = n & 1;

        // ---- layer 1: two h columns -> wave-private LDS (pre1 precomputed;
        //      critical path after s: 1 fma + 4-instr tanh).
        float ha = tanh_e2(fmaf(w1s.x, s, pre1.x));
        float hb = tanh_e2(fmaf(w1s.y, s, pre1.y));
        *reinterpret_cast<float2*>(&h1buf[wv][hoff]) = make_float2(ha, hb);
        __builtin_amdgcn_wave_barrier();   // order in-wave LDS write -> reads

        // next step's x + next pre1 (broadcast read, off critical path)
        float2 xnp = xbuf[(n + 1) & (SEQ - 1)];
        float xn1 = ch ? xnp.y : xnp.x;
        pre1 = make_float2(fmaf(w1x.x, xn1, b1v.x), fmaf(w1x.y, xn1, b1v.y));

        // ---- layer 2: 4 cols x 16 K per lane; 4 b128 reads, 32 v_pk_fma_f32.
        f32x2 a0 = {0.0f, 0.0f}, a1 = {0.0f, 0.0f};
        f32x2 a2 = {0.0f, 0.0f}, a3 = {0.0f, 0.0f};
        #pragma unroll
        for (int i = 0; i < 4; ++i) {
            float4 hv = h4[i];
            f32x2 h0 = {hv.x, hv.y};
            f32x2 h1p = {hv.z, hv.w};
            a0 = __builtin_elementwise_fma(wc0[2 * i], h0, a0);
            a1 = __builtin_elementwise_fma(wc1[2 * i], h0, a1);
            a2 = __builtin_elementwise_fma(wc2[2 * i], h0, a2);
            a3 = __builtin_elementwise_fma(wc3[2 * i], h0, a3);
            a0 = __builtin_elementwise_fma(wc0[2 * i + 1], h1p, a0);
            a1 = __builtin_elementwise_fma(wc1[2 * i + 1], h1p, a1);
            a2 = __builtin_elementwise_fma(wc2[2 * i + 1], h1p, a2);
            a3 = __builtin_elementwise_fma(wc3[2 * i + 1], h1p, a3);
        }
        __builtin_amdgcn_wave_barrier();   // keep reads before next iter's write

        // ---- K-eighth combine within 8-lane group: xor1, xor2, xor4(eff).
        float p0 = a0.x + a0.y, p1 = a1.x + a1.y;
        float p2 = a2.x + a2.y, p3 = a3.x + a3.y;
        p0 = dpp_add<0xB1>(p0);  p1 = dpp_add<0xB1>(p1);   // quad_perm(1,0,3,2)
        p2 = dpp_add<0xB1>(p2);  p3 = dpp_add<0xB1>(p3);
        p0 = dpp_add<0x4E>(p0);  p1 = dpp_add<0x4E>(p1);   // quad_perm(2,3,0,1)
        p2 = dpp_add<0x4E>(p2);  p3 = dpp_add<0x4E>(p3);
        p0 = dpp_add<0x141>(p0); p1 = dpp_add<0x141>(p1);  // row_half_mirror
        p2 = dpp_add<0x141>(p2); p3 = dpp_add<0x141>(p3);

        // ---- layer 2 tanh + W3 col-1 dot (z duplicated x8; w3 prescaled).
        float z = tanh_e2(p0 + b2v.x) * w3s0;
        z = fmaf(tanh_e2(p1 + b2v.y), w3s1, z);
        z = fmaf(tanh_e2(p2 + b2v.z), w3s2, z);
        z = fmaf(tanh_e2(p3 + b2v.w), w3s3, z);

        // ---- wave64 sum: row_shr/bcast cascade; full sum lands in lane 63.
        z = dpp_add<0x111>(z);   // row_shr:1
        z = dpp_add<0x112>(z);   // row_shr:2
        z = dpp_add<0x114>(z);   // row_shr:4
        z = dpp_add<0x118>(z);   // row_shr:8
        z = dpp_add<0x142>(z);   // row_bcast:15
        z = dpp_add<0x143>(z);   // row_bcast:31

        if (l == 63) ybuf[par][wv] = z;    // this wave's 32-col partial
        __syncthreads();   // ONE barrier serves BOTH chains' steps

        const float4 yv = *reinterpret_cast<const float4*>(&ybuf[par][4 * ch]);
        s = s + ((yv.x + yv.y) + (yv.z + yv.w)) + b31;

        // ---- out batching: wave0 stores chain A, wave4 stores chain B.
        if (w == 0) {
            if (l == (n & 63)) s_hold = s;
            if ((n & 63) == 63) out[(n - 63 + l) * BATCH + b0 + ch] = s_hold;
        }
    }
}

extern "C" void kernel_launch(void* const* d_in, const int* in_sizes, int n_in,
                              void* d_out, int out_size, void* d_ws, size_t ws_size,
                              hipStream_t stream) {
    const float* x  = (const float*)d_in[0];
    const float* W1 = (const float*)d_in[1];
    const float* b1 = (const float*)d_in[2];
    const float* W2 = (const float*)d_in[3];
    const float* b2 = (const float*)d_in[4];
    const float* W3 = (const float*)d_in[5];
    const float* b3 = (const float*)d_in[6];
    float* out = (float*)d_out;

    dim3 grid(BATCH / 2);   // two chains per block (separate wave-groups)
    dim3 block(512);        // 8 waves: 0-3 chain A, 4-7 chain B
    odenet_scan_kernel<<<grid, block, 0, stream>>>(x, W1, b1, W2, b2, W3, b3, out);
}